// Round 2
// baseline (1442.866 us; speedup 1.0000x reference)
//
#include <hip/hip_runtime.h>
#include <cstddef>

#define DEV static __device__ __forceinline__

// ---------------------------------------------------------------------------
// Problem constants
//   B=8, Lt=32, Lv=64, L=96, Din=512, D=256, H=4, dh=64, layers=6
//   x_vis: (8,64,257,1408)  noise: (8,1000,64)  out: (8,4,257,1408)
// ---------------------------------------------------------------------------

constexpr int BM = 32, BN = 64, KC = 32;

enum { AM_PLAIN = 0, AM_SUM4 = 1, AM_LN = 2 };
enum { EP_BIAS = 0, EP_RELU = 1, EP_RESID = 2, EP_RESIDLN = 3, EP_SCALEMOD = 4, EP_EMB = 5 };

DEV float4 ld4(const float* p) { return *reinterpret_cast<const float4*>(p); }
DEV void st4(float* p, float4 v) { *reinterpret_cast<float4*>(p) = v; }
DEV float4 f4z() { float4 r; r.x = r.y = r.z = r.w = 0.f; return r; }
DEV float4 f4add(float4 a, float4 b) { a.x += b.x; a.y += b.y; a.z += b.z; a.w += b.w; return a; }
DEV float4 f4fma(float s, float4 b, float4 a) {
  a.x = fmaf(s, b.x, a.x); a.y = fmaf(s, b.y, a.y);
  a.z = fmaf(s, b.z, a.z); a.w = fmaf(s, b.w, a.w); return a;
}
DEV float hsum4(float4 v) { return v.x + v.y + v.z + v.w; }

// Two-pass row stats (mu, rsqrt(var+eps)) for 32 rows x 256 cols. 256 threads.
DEV void row_stats(const float* __restrict__ src, int ldsrc, int r0, int t,
                   float (*red)[8], float* s_mu, float* s_rs)
{
  const int row = t >> 3, tq = t & 7;
  const float* p = src + (size_t)(r0 + row) * ldsrc + tq * 32;
  float s = 0.f;
#pragma unroll
  for (int i = 0; i < 8; ++i) { float4 v = ld4(p + i * 4); s += hsum4(v); }
  red[row][tq] = s;
  __syncthreads();
  if (t < BM) {
    float a = 0.f;
#pragma unroll
    for (int i = 0; i < 8; ++i) a += red[t][i];
    s_mu[t] = a * (1.f / 256.f);
  }
  __syncthreads();
  const float m = s_mu[row];
  float q = 0.f;
#pragma unroll
  for (int i = 0; i < 8; ++i) {
    float4 v = ld4(p + i * 4);
    float a = v.x - m, b = v.y - m, c = v.z - m, d = v.w - m;
    q += a * a + b * b + c * c + d * d;
  }
  red[row][tq] = q;
  __syncthreads();
  if (t < BM) {
    float a = 0.f;
#pragma unroll
    for (int i = 0; i < 8; ++i) a += red[t][i];
    float var = a * (1.f / 256.f) + 1e-5f;
    float r = rsqrtf(var);
    r = r * (1.5f - 0.5f * var * r * r);   // Newton refine -> ~IEEE accurate
    s_rs[t] = r;
  }
  __syncthreads();
}

// ---------------------------------------------------------------------------
// Generic tiled f32 GEMM:  out = A @ W^T (+ fused prologue/epilogue)
//   A: [M][lda] (row-major, K contiguous); W: [N][wld]; out: [M*][ldo]
//   BM=32, BN=64, 256 threads, each thread 2x4 outputs.
//   AMODE: plain | sum of 4 K-split partials | LayerNorm(A) (K==256)
//   EPI:   bias | bias+relu | bias+resid | bias+LN(resid) | (v+b)*16+mod | z-gated bias
//   ROWMAP: 0 direct, 1 txt rows -> b*96+j, 2 vis rows -> b*96+32+j
// ---------------------------------------------------------------------------
template<int AMODE, int EPI, int ROWMAP>
__launch_bounds__(256)
__global__ void gemm_k(const float* __restrict__ A, int lda, int a_zoff,
                       const float* __restrict__ W, int wld,
                       const float* __restrict__ bias,
                       float* __restrict__ out, int out_zstride, int ldo,
                       int M, int N, int Kd,
                       const float* __restrict__ lnS, const float* __restrict__ lnB,
                       const float* __restrict__ R,
                       const float* __restrict__ rS, const float* __restrict__ rB,
                       const float* __restrict__ mod0, const float* __restrict__ mod3)
{
  (void)M; (void)N;
  __shared__ float As[BM][36];         // row-major, stride 36 (conflict-free a reads)
  __shared__ float Bt[KC][68];         // k-major transposed, stride 68 (2-way max)
  __shared__ float red[BM][8];
  __shared__ float s_mu[BM], s_rs[BM];

  const int t  = threadIdx.x;
  const int r0 = blockIdx.x * BM;
  const int c0 = blockIdx.y * BN;
  const int z  = blockIdx.z;
  const float* Ab = A + (size_t)z * a_zoff;
  const float* Wb = W + (size_t)z * a_zoff;
  float* outb = out + (size_t)z * out_zstride;

  if (AMODE == AM_LN) row_stats(A, lda, r0, t, red, s_mu, s_rs);

  const int arow = t >> 3, akq = t & 7;   // staging: 32 rows x 8 k-quads
  const int ty = t >> 4, tx = t & 15;     // compute: 16x16

  float4 acc0 = f4z(), acc1 = f4z();

  for (int kb = 0; kb < Kd; kb += KC) {
    __syncthreads();
    // --- stage A (32 x 32 chunk) ---
    float4 av;
    if (AMODE == AM_SUM4) {
      const float* p = Ab + (size_t)(r0 + arow) * lda + kb + akq * 4;
      float4 v0 = ld4(p), v1 = ld4(p + 393216), v2 = ld4(p + 786432), v3 = ld4(p + 1179648);
      av = f4add(f4add(v0, v1), f4add(v2, v3));
    } else {
      av = ld4(Ab + (size_t)(r0 + arow) * lda + kb + akq * 4);
    }
    if (AMODE == AM_LN) {
      const float m = s_mu[arow], r = s_rs[arow];
      const float4 sv = ld4(lnS + kb + akq * 4), bv = ld4(lnB + kb + akq * 4);
      av.x = (av.x - m) * r * sv.x + bv.x;
      av.y = (av.y - m) * r * sv.y + bv.y;
      av.z = (av.z - m) * r * sv.z + bv.z;
      av.w = (av.w - m) * r * sv.w + bv.w;
    }
    st4(&As[arow][akq * 4], av);
    // --- stage W transposed (64 x 32 chunk) ---
    {
      const float* wp = Wb + (size_t)(c0 + arow) * wld + kb + akq * 4;
      float4 w0 = ld4(wp);
      float4 w1 = ld4(wp + (size_t)32 * wld);
      Bt[akq * 4 + 0][arow] = w0.x; Bt[akq * 4 + 1][arow] = w0.y;
      Bt[akq * 4 + 2][arow] = w0.z; Bt[akq * 4 + 3][arow] = w0.w;
      Bt[akq * 4 + 0][arow + 32] = w1.x; Bt[akq * 4 + 1][arow + 32] = w1.y;
      Bt[akq * 4 + 2][arow + 32] = w1.z; Bt[akq * 4 + 3][arow + 32] = w1.w;
    }
    __syncthreads();
    // --- compute ---
#pragma unroll
    for (int kq = 0; kq < 8; ++kq) {
      float4 a0 = ld4(&As[ty * 2 + 0][kq * 4]);
      float4 a1 = ld4(&As[ty * 2 + 1][kq * 4]);
      float4 b0 = ld4(&Bt[kq * 4 + 0][tx * 4]);
      float4 b1 = ld4(&Bt[kq * 4 + 1][tx * 4]);
      float4 b2 = ld4(&Bt[kq * 4 + 2][tx * 4]);
      float4 b3 = ld4(&Bt[kq * 4 + 3][tx * 4]);
      acc0 = f4fma(a0.x, b0, acc0); acc0 = f4fma(a0.y, b1, acc0);
      acc0 = f4fma(a0.z, b2, acc0); acc0 = f4fma(a0.w, b3, acc0);
      acc1 = f4fma(a1.x, b0, acc1); acc1 = f4fma(a1.y, b1, acc1);
      acc1 = f4fma(a1.z, b2, acc1); acc1 = f4fma(a1.w, b3, acc1);
    }
  }

  if (EPI == EP_RESIDLN) {
    __syncthreads();
    row_stats(R, 256, r0, t, red, s_mu, s_rs);
  }

  const int gc = c0 + tx * 4;
  const float4 bb = ld4(bias + gc);
#pragma unroll
  for (int dr = 0; dr < 2; ++dr) {
    const int gr = r0 + ty * 2 + dr;
    float4 v = (dr == 0) ? acc0 : acc1;
    if (EPI == EP_BIAS) v = f4add(v, bb);
    if (EPI == EP_RELU) {
      v = f4add(v, bb);
      v.x = fmaxf(v.x, 0.f); v.y = fmaxf(v.y, 0.f);
      v.z = fmaxf(v.z, 0.f); v.w = fmaxf(v.w, 0.f);
    }
    if (EPI == EP_RESID) {
      float4 rv = ld4(R + (size_t)gr * 256 + gc);
      v = f4add(f4add(v, bb), rv);
    }
    if (EPI == EP_RESIDLN) {
      const float m = s_mu[ty * 2 + dr], rr = s_rs[ty * 2 + dr];
      float4 rv = ld4(R + (size_t)gr * 256 + gc);
      float4 sv = ld4(rS + gc), bv2 = ld4(rB + gc);
      v = f4add(v, bb);
      v.x += (rv.x - m) * rr * sv.x + bv2.x;
      v.y += (rv.y - m) * rr * sv.y + bv2.y;
      v.z += (rv.z - m) * rr * sv.z + bv2.z;
      v.w += (rv.w - m) * rr * sv.w + bv2.w;
    }
    if (EPI == EP_SCALEMOD) {
      v = f4add(v, bb);
      const float* mm = ((gr % 96) < 32) ? mod0 : mod3;
      float4 mv = ld4(mm + gc);
      v.x = v.x * 16.f + mv.x; v.y = v.y * 16.f + mv.y;
      v.z = v.z * 16.f + mv.z; v.w = v.w * 16.f + mv.w;
    }
    if (EPI == EP_EMB) {
      if (z == 0) v = f4add(v, bb);
    }
    int og = gr;
    if (ROWMAP == 1) og = (gr >> 5) * 96 + (gr & 31);
    if (ROWMAP == 2) og = (gr >> 6) * 96 + 32 + (gr & 63);
    st4(outb + (size_t)og * ldo + gc, v);
  }
}

// ---------------------------------------------------------------------------
// Attention: one block per (b, head, third-of-rows). qkv row layout:
// [row][ q(0:256) | k(256:512) | v(512:768) ], head h at h*64.
// 128 threads = 32 rows x 4 e-quarters. K,V staged in LDS; scores in LDS.
// ---------------------------------------------------------------------------
__launch_bounds__(128)
__global__ void attn_k(const float* __restrict__ qkv, float* __restrict__ attno)
{
  __shared__ float kb[96][64];
  __shared__ float vb[96][64];
  __shared__ float sc[32][100];
  const int w = blockIdx.x;
  const int b = w / 12, rem = w % 12;
  const int h = rem / 3, third = rem % 3;
  const int t = threadIdx.x;
  const float* base = qkv + (size_t)b * 96 * 768;
#pragma unroll
  for (int it = 0; it < 12; ++it) {
    int fi = it * 128 + t;                 // 1536 float4s
    int j = fi >> 4, e4 = fi & 15;
    const float* src = base + (size_t)j * 768 + 256 + h * 64 + e4 * 4;
    st4(&kb[j][e4 * 4], ld4(src));
    st4(&vb[j][e4 * 4], ld4(src + 256));
  }
  __syncthreads();
  const int i = t >> 2, q = t & 3;
  const int grow = b * 96 + third * 32 + i;
  const float* qp = qkv + (size_t)grow * 768 + h * 64 + q * 16;
  const float4 qf0 = ld4(qp), qf1 = ld4(qp + 4), qf2 = ld4(qp + 8), qf3 = ld4(qp + 12);
  float m = -1e30f;
  for (int j = 0; j < 96; ++j) {
    const float* kr = &kb[j][q * 16];
    float4 k0 = ld4(kr), k1 = ld4(kr + 4), k2 = ld4(kr + 8), k3 = ld4(kr + 12);
    float s = qf0.x * k0.x + qf0.y * k0.y + qf0.z * k0.z + qf0.w * k0.w
            + qf1.x * k1.x + qf1.y * k1.y + qf1.z * k1.z + qf1.w * k1.w
            + qf2.x * k2.x + qf2.y * k2.y + qf2.z * k2.z + qf2.w * k2.w
            + qf3.x * k3.x + qf3.y * k3.y + qf3.z * k3.z + qf3.w * k3.w;
    s += __shfl_xor(s, 1);
    s += __shfl_xor(s, 2);
    s *= 0.125f;                            // 1/sqrt(64)
    if (q == 0) sc[i][j] = s;
    m = fmaxf(m, s);
  }
  __syncthreads();
  float l = 0.f;
  for (int jj = q; jj < 96; jj += 4) l += __expf(sc[i][jj] - m);
  l += __shfl_xor(l, 1);
  l += __shfl_xor(l, 2);
  const float inv = 1.f / l;
  float4 a0 = f4z(), a1 = f4z(), a2 = f4z(), a3 = f4z();
  for (int j = 0; j < 96; ++j) {
    float p = __expf(sc[i][j] - m) * inv;
    const float* vr = &vb[j][q * 16];
    a0 = f4fma(p, ld4(vr), a0);
    a1 = f4fma(p, ld4(vr + 4), a1);
    a2 = f4fma(p, ld4(vr + 8), a2);
    a3 = f4fma(p, ld4(vr + 12), a3);
  }
  float* op = attno + (size_t)grow * 256 + h * 64 + q * 16;
  st4(op, a0); st4(op + 4, a1); st4(op + 8, a2); st4(op + 12, a3);
}

// ---------------------------------------------------------------------------
// Final LN + logits (rows 32..95 per batch) + zero indicator counters.
// One block per batch; thread = (row i, quarter q).
// ---------------------------------------------------------------------------
__launch_bounds__(256)
__global__ void logits_k(const float* __restrict__ x, const float* __restrict__ s2,
                         const float* __restrict__ b2,
                         const float* __restrict__ Wlog, const float* __restrict__ blog,
                         float* __restrict__ logits, float* __restrict__ ind)
{
  const int b = blockIdx.x, t = threadIdx.x;
  ind[b * 256 + t] = 0.f;
  const int i = t >> 2, q = t & 3;
  const float* row = x + (size_t)(b * 96 + 32 + i) * 256 + q * 64;
  float4 v[16];
  float s = 0.f;
#pragma unroll
  for (int n = 0; n < 16; ++n) { v[n] = ld4(row + n * 4); s += hsum4(v[n]); }
  s += __shfl_xor(s, 1); s += __shfl_xor(s, 2);
  const float mu = s * (1.f / 256.f);
  float qs = 0.f;
#pragma unroll
  for (int n = 0; n < 16; ++n) {
    float a = v[n].x - mu, c = v[n].y - mu, d2 = v[n].z - mu, e = v[n].w - mu;
    qs += a * a + c * c + d2 * d2 + e * e;
  }
  qs += __shfl_xor(qs, 1); qs += __shfl_xor(qs, 2);
  float var = qs * (1.f / 256.f) + 1e-5f;
  float r = rsqrtf(var);
  r = r * (1.5f - 0.5f * var * r * r);
  float d = 0.f;
#pragma unroll
  for (int n = 0; n < 16; ++n) {
    const int k = q * 64 + n * 4;
    float4 sv = ld4(s2 + k), bv = ld4(b2 + k), wv = ld4(Wlog + k);
    d += ((v[n].x - mu) * r * sv.x + bv.x) * wv.x;
    d += ((v[n].y - mu) * r * sv.y + bv.y) * wv.y;
    d += ((v[n].z - mu) * r * sv.z + bv.z) * wv.z;
    d += ((v[n].w - mu) * r * sv.w + bv.w) * wv.w;
  }
  d += __shfl_xor(d, 1); d += __shfl_xor(d, 2);
  if (q == 0) logits[b * 64 + i] = d + blog[0];
}

// ---------------------------------------------------------------------------
// Perturbed top-4: one wave per sample (lane j holds value j). 4 argmax
// butterfly rounds (tie -> lower index, matching lax.top_k), sort indices,
// count via atomics (exact integer f32 sums -> deterministic).
// ---------------------------------------------------------------------------
__launch_bounds__(256)
__global__ void topk_k(const float* __restrict__ logits, const float* __restrict__ noise,
                       float* __restrict__ ind)
{
  const int t = threadIdx.x;
  const int lane = t & 63;
  const int s = blockIdx.x * 4 + (t >> 6);
  const int b = s / 1000, si = s % 1000;
  float cur = logits[b * 64 + lane] +
              noise[((size_t)(b * 1000 + si)) * 64 + lane] * 0.05f;
  int w0 = 0, w1 = 0, w2 = 0, w3 = 0;
#pragma unroll
  for (int rr = 0; rr < 4; ++rr) {
    float v = cur; int idx = lane;
#pragma unroll
    for (int st = 1; st < 64; st <<= 1) {
      float ov = __shfl_xor(v, st);
      int oi = __shfl_xor(idx, st);
      if (ov > v || (ov == v && oi < idx)) { v = ov; idx = oi; }
    }
    if (rr == 0) w0 = idx; else if (rr == 1) w1 = idx;
    else if (rr == 2) w2 = idx; else w3 = idx;
    if (lane == idx) cur = -1e30f;
  }
  int a, bq;
#define CSWP(X, Y) a = min(X, Y); bq = max(X, Y); X = a; Y = bq;
  CSWP(w0, w1) CSWP(w2, w3) CSWP(w0, w2) CSWP(w1, w3) CSWP(w1, w2)
#undef CSWP
  if (lane < 4) {
    int wk = lane == 0 ? w0 : lane == 1 ? w1 : lane == 2 ? w2 : w3;
    atomicAdd(&ind[b * 256 + lane * 64 + wk], 1.0f);
  }
}

// ---------------------------------------------------------------------------
// out[b,k,:,:] = sum_d ind[b,k,d]/1000 * x_vis[b,d,:,:]
// Sparse: skip d where all 4 weights are zero (wave-uniform branch) ->
// reads only the selected slabs per batch instead of all 741 MB.
// ---------------------------------------------------------------------------
__launch_bounds__(256)
__global__ void out_k(const float* __restrict__ xvis, const float* __restrict__ ind,
                      float* __restrict__ out)
{
  __shared__ float wsh[256];
  const int b = blockIdx.y, c = blockIdx.x, t = threadIdx.x;
  wsh[t] = ind[b * 256 + t] * 1e-3f;
  __syncthreads();
  const size_t off = (size_t)c * 1024 + t * 4;
  if (off >= 361856) return;
  const float* xb = xvis + (size_t)b * 64 * 361856 + off;
  float4 a0 = f4z(), a1 = f4z(), a2 = f4z(), a3 = f4z();
  for (int d = 0; d < 64; ++d) {
    const float w0 = wsh[d], w1 = wsh[64 + d], w2 = wsh[128 + d], w3 = wsh[192 + d];
    if (w0 != 0.f || w1 != 0.f || w2 != 0.f || w3 != 0.f) {
      float4 v = ld4(xb + (size_t)d * 361856);
      a0 = f4fma(w0, v, a0); a1 = f4fma(w1, v, a1);
      a2 = f4fma(w2, v, a2); a3 = f4fma(w3, v, a3);
    }
  }
  float* ob = out + (size_t)b * 4 * 361856 + off;
  st4(ob, a0); st4(ob + 361856, a1);
  st4(ob + 2 * 361856, a2); st4(ob + 3 * 361856, a3);
}

// ---------------------------------------------------------------------------
extern "C" void kernel_launch(void* const* d_in, const int* in_sizes, int n_in,
                              void* d_out, int out_size, void* d_ws, size_t ws_size,
                              hipStream_t stream)
{
  (void)in_sizes; (void)n_in; (void)out_size; (void)ws_size;
  const float* x_vis  = (const float*)d_in[0];
  const float* x_txt  = (const float*)d_in[1];
  const float* Wt     = (const float*)d_in[2];
  const float* bt     = (const float*)d_in[3];
  const float* Wv     = (const float*)d_in[4];
  const float* bv     = (const float*)d_in[5];
  const float* We     = (const float*)d_in[6];
  const float* be     = (const float*)d_in[7];
  const float* mod_emb= (const float*)d_in[8];
  const float* Wqkv   = (const float*)d_in[9];
  const float* bqkv   = (const float*)d_in[10];
  const float* Wo     = (const float*)d_in[11];
  const float* bo     = (const float*)d_in[12];
  const float* ln1_s  = (const float*)d_in[13];
  const float* ln1_b  = (const float*)d_in[14];
  const float* W1     = (const float*)d_in[15];
  const float* b1     = (const float*)d_in[16];
  const float* W2     = (const float*)d_in[17];
  const float* b2     = (const float*)d_in[18];
  const float* ln2_s  = (const float*)d_in[19];
  const float* ln2_b  = (const float*)d_in[20];
  const float* Wlog   = (const float*)d_in[21];
  const float* blog   = (const float*)d_in[22];
  const float* noise  = (const float*)d_in[23];
  float* outp = (float*)d_out;

  float* ws     = (float*)d_ws;
  float* P      = ws;                    // 4 * 768*512 K-split partials
  float* xbuf0  = P + 1572864;           // 768*256
  float* qkvb   = xbuf0 + 196608;        // 768*768
  float* attno  = qkvb + 589824;         // 768*256
  float* y1     = attno + 196608;
  float* h1     = y1 + 196608;
  float* y2a    = h1 + 196608;
  float* y2b    = y2a + 196608;
  float* logits = y2b + 196608;          // 8*64
  float* ind    = logits + 512;          // 8*4*64

  const float* np = nullptr;

  // ---- embeds (K-split x4 into partials P, bias folded into chunk 0) ----
  gemm_k<AM_PLAIN, EP_EMB, 1><<<dim3(8, 8, 4), 256, 0, stream>>>(
      x_txt, 2048, 512, Wt, 2048, bt, P, 393216, 512, 256, 512, 512,
      np, np, np, np, np, np, np);
  gemm_k<AM_PLAIN, EP_EMB, 2><<<dim3(16, 8, 4), 256, 0, stream>>>(
      x_vis, 361856, 352, Wv, 1408, bv, P, 393216, 512, 512, 512, 352,
      np, np, np, np, np, np, np);
  // ---- x = (sum(P) @ We^T + be) * 16 + mod ----
  gemm_k<AM_SUM4, EP_SCALEMOD, 0><<<dim3(24, 4), 256, 0, stream>>>(
      P, 512, 0, We, 512, be, xbuf0, 0, 256, 768, 256, 512,
      np, np, np, np, np, mod_emb, mod_emb + 768);

  const float* xin = xbuf0;
  const float* prevS = nullptr; const float* prevB = nullptr;
  float* y2bufs[2] = { y2a, y2b };
  for (int i = 0; i < 6; ++i) {
    const float* WqkvI = Wqkv + (size_t)i * 768 * 256;
    const float* bqkvI = bqkv + i * 768;
    const float* WoI = Wo + (size_t)i * 65536;
    const float* boI = bo + i * 256;
    const float* s1I = ln1_s + i * 256;
    const float* b1nI = ln1_b + i * 256;
    const float* W1I = W1 + (size_t)i * 65536;
    const float* b1I = b1 + i * 256;
    const float* W2I = W2 + (size_t)i * 65536;
    const float* b2I = b2 + i * 256;
    float* y2cur = y2bufs[i & 1];

    if (i == 0)
      gemm_k<AM_PLAIN, EP_BIAS, 0><<<dim3(24, 12), 256, 0, stream>>>(
          xin, 256, 0, WqkvI, 256, bqkvI, qkvb, 0, 768, 768, 768, 256,
          np, np, np, np, np, np, np);
    else
      gemm_k<AM_LN, EP_BIAS, 0><<<dim3(24, 12), 256, 0, stream>>>(
          xin, 256, 0, WqkvI, 256, bqkvI, qkvb, 0, 768, 768, 768, 256,
          prevS, prevB, np, np, np, np, np);

    attn_k<<<dim3(96), 128, 0, stream>>>(qkvb, attno);

    if (i == 0)
      gemm_k<AM_PLAIN, EP_RESID, 0><<<dim3(24, 4), 256, 0, stream>>>(
          attno, 256, 0, WoI, 256, boI, y1, 0, 256, 768, 256, 256,
          np, np, xin, np, np, np, np);
    else
      gemm_k<AM_PLAIN, EP_RESIDLN, 0><<<dim3(24, 4), 256, 0, stream>>>(
          attno, 256, 0, WoI, 256, boI, y1, 0, 256, 768, 256, 256,
          np, np, xin, prevS, prevB, np, np);

    gemm_k<AM_LN, EP_RELU, 0><<<dim3(24, 4), 256, 0, stream>>>(
        y1, 256, 0, W1I, 256, b1I, h1, 0, 256, 768, 256, 256,
        s1I, b1nI, np, np, np, np, np);

    gemm_k<AM_PLAIN, EP_RESIDLN, 0><<<dim3(24, 4), 256, 0, stream>>>(
        h1, 256, 0, W2I, 256, b2I, y2cur, 0, 256, 768, 256, 256,
        np, np, y1, s1I, b1nI, np, np);

    xin = y2cur;
    prevS = ln2_s + i * 256;
    prevB = ln2_b + i * 256;
  }

  logits_k<<<dim3(8), 256, 0, stream>>>(xin, prevS, prevB, Wlog, blog, logits, ind);
  topk_k<<<dim3(2000), 256, 0, stream>>>(logits, noise, ind);
  out_k<<<dim3(354, 8), 256, 0, stream>>>(x_vis, ind, outp);
}